// Round 3
// baseline (160.005 us; speedup 1.0000x reference)
//
#include <hip/hip_runtime.h>
#include <math.h>

typedef __attribute__((ext_vector_type(8))) short short8;
typedef __attribute__((ext_vector_type(4))) float f32x4;

namespace {
constexpr int NEL   = 4;
constexpr int NEXP  = 16;
constexpr int Bb    = 128;
constexpr int Aa    = 128;
constexpr int Cc    = 256;
constexpr int FATOM = 176;
constexpr int FPAIR = 32;
constexpr int FIN   = 384;
constexpr int HH1   = 128;
constexpr int HH2   = 96;
constexpr int NP    = Bb * Cc;               // 32768
constexpr int TILE_P = 16;                   // pairs per tile (1 block = 2 waves)
constexpr int BUCKET_CAP = 4096;             // pairs per expert cap (input ~2048 +- 44)
constexpr int TMAX = BUCKET_CAP / TILE_P;    // 256 tiles per expert

// ws int offsets
constexpr int WS_COUNTS = 0;                 // 16 ints
constexpr int WS_BUCKET = 64;                // 16 * 4096 ints
constexpr int WS_BF     = 65600;             // shorts from here (byte 262400, 16B aligned)
constexpr int SYM_N   = Bb * Aa * FATOM;     // 2,883,584
constexpr int PAIR_N  = Bb * Cc * FPAIR;     // 1,048,576
constexpr int W1T_N   = NEXP * HH1 * FIN;    // 786,432
constexpr int W2T_N   = NEXP * HH2 * HH1;    // 196,608
}

__device__ inline float bf2f(short s) {
    unsigned u = ((unsigned)(unsigned short)s) << 16;
    return __builtin_bit_cast(float, u);
}
__device__ inline short f2bf(float f) {
    unsigned u = __builtin_bit_cast(unsigned, f);
    unsigned r = (u + 0x7FFFu + ((u >> 16) & 1u)) >> 16;
    return (short)r;
}

// ---- convert sym_features + pair_features fp32 -> bf16 (vectorized) ----
__global__ void k_cvt_x(const float* __restrict__ sym, const float* __restrict__ pairf,
                        short* __restrict__ symb, short* __restrict__ pairfb)
{
    int i = blockIdx.x * 256 + threadIdx.x;          // one float4 per thread
    constexpr int NS4 = SYM_N / 4;
    constexpr int NT4 = NS4 + PAIR_N / 4;
    if (i >= NT4) return;
    const float4* src; short* dst; int j;
    if (i < NS4) { src = (const float4*)sym;   dst = symb;   j = i; }
    else         { src = (const float4*)pairf; dst = pairfb; j = i - NS4; }
    float4 v = src[j];
    short4 o;
    o.x = f2bf(v.x); o.y = f2bf(v.y); o.z = f2bf(v.z); o.w = f2bf(v.w);
    *(short4*)(dst + 4 * (size_t)j) = o;
}

// ---- fused: W1/W2 LDS-tiled transpose+convert  AND  expert index+append ----
// blocks [0,768): W1 tiles; [768,960): W2 tiles; [960,1088): index
__global__ __launch_bounds__(256) void k_prep(
    const float* __restrict__ W1, const float* __restrict__ W2,
    short* __restrict__ w1tb, short* __restrict__ w2tb,
    const int* __restrict__ conn, const int* __restrict__ elements,
    int* __restrict__ counts, int* __restrict__ bucket,
    float* __restrict__ out)
{
    int bid = blockIdx.x;
    int t = threadIdx.x;
    if (bid < 960) {
        __shared__ float T[32][33];
        const float* src; short* dst; int K, N, k0, n0;
        if (bid < 768) {
            int e = bid / 48, tl = bid % 48;
            K = FIN; N = HH1; k0 = (tl % 12) * 32; n0 = (tl / 12) * 32;
            src = W1 + (size_t)e * K * N;
            dst = w1tb + (size_t)e * N * K;
        } else {
            int b2 = bid - 768;
            int e = b2 / 12, tl = b2 % 12;
            K = HH1; N = HH2; k0 = (tl % 4) * 32; n0 = (tl / 4) * 32;
            src = W2 + (size_t)e * K * N;
            dst = w2tb + (size_t)e * N * K;
        }
        int tx = t & 31, ty = t >> 5;                 // 0..31, 0..7
#pragma unroll
        for (int j = 0; j < 4; ++j) {
            int r = ty + 8 * j;
            T[r][tx] = src[(size_t)(k0 + r) * N + n0 + tx];
        }
        __syncthreads();
#pragma unroll
        for (int j = 0; j < 4; ++j) {
            int r = ty + 8 * j;
            dst[(size_t)(n0 + r) * K + k0 + tx] = f2bf(T[tx][r]);
        }
    } else {
        int p = (bid - 960) * 256 + t;
        if (p >= NP) return;
        int c0 = conn[2 * p], c1 = conn[2 * p + 1];
        int e = -1;
        if (c0 != -1) {
            int b = p / Cc;
            int i0 = b * Aa + c0; if (i0 < 0) i0 += Bb * Aa;
            int i1 = b * Aa + c1; if (i1 < 0) i1 += Bb * Aa;
            e = elements[i0] * NEL + elements[i1];
        }
        if (e < 0 || e >= NEXP) {
            out[2 * p] = 0.f; out[2 * p + 1] = 0.f;
        } else {
            int pos = atomicAdd(&counts[e], 1);
            if (pos < BUCKET_CAP) bucket[e * BUCKET_CAP + pos] = p;
        }
    }
}

// ---- MFMA MoE: one 16-pair tile per block, split across 2 waves ----
__device__ inline const short* xptr(const short* symb, const short* pfb,
                                    int i0, int i1, int p, int kk)
{
    if (kk < FATOM)     return symb + (size_t)i0 * FATOM + kk;
    if (kk < 2 * FATOM) return symb + (size_t)i1 * FATOM + (kk - FATOM);
    return pfb + (size_t)p * FPAIR + (kk - 2 * FATOM);
}

__global__ __launch_bounds__(128, 4) void k_moe(
    const int* __restrict__ counts, const int* __restrict__ bucket,
    const int* __restrict__ conn,
    const short* __restrict__ symb, const short* __restrict__ pairfb,
    const short* __restrict__ w1tb, const short* __restrict__ w2tb,
    const float* __restrict__ b1, const float* __restrict__ b2,
    const float* __restrict__ W3, const float* __restrict__ b3,
    float* __restrict__ out)
{
    __shared__ short H1s[TILE_P * HH1];        // 4 KB, granule-XOR swizzled
    __shared__ short H2s[TILE_P * 104];        // 3.25 KB, stride 104
    __shared__ int rows_p[TILE_P], rows_i0[TILE_P], rows_i1[TILE_P];

    int e    = blockIdx.x >> 8;                // / TMAX
    int tile = blockIdx.x & (TMAX - 1);
    int cnt_e = counts[e];
    if (cnt_e > BUCKET_CAP) cnt_e = BUCKET_CAP;
    int base = tile * TILE_P;
    if (base >= cnt_e) return;
    int cnt = cnt_e - base; if (cnt > TILE_P) cnt = TILE_P;

    int t = threadIdx.x;
    if (t < TILE_P) {
        int idx = base + ((t < cnt) ? t : 0);
        int p = bucket[e * BUCKET_CAP + idx];
        int b = p / Cc;
        rows_p[t]  = p;
        rows_i0[t] = b * Aa + conn[2 * p];
        rows_i1[t] = b * Aa + conn[2 * p + 1];
    }
    __syncthreads();

    int w  = t >> 6;                            // wave 0/1
    int lr = t & 15, lg = (t >> 4) & 3;

    int i0a = rows_i0[lr], i1a = rows_i1[lr], pa = rows_p[lr];

    // -------- Layer 1: H1[16x128] = celu(X[16x384] @ W1 + b1); wave w owns n-cols [w*64, w*64+64)
    const short* w1t_e = w1tb + (size_t)e * HH1 * FIN;
    f32x4 acc[4];
#pragma unroll
    for (int j = 0; j < 4; ++j) {
        float bv = b1[e * HH1 + (w * 4 + j) * 16 + lr];
        acc[j] = (f32x4){bv, bv, bv, bv};
    }
    for (int ks = 0; ks < 12; ++ks) {
        int kk = ks * 32 + 8 * lg;
        short8 a0 = *(const short8*)xptr(symb, pairfb, i0a, i1a, pa, kk);
#pragma unroll
        for (int j = 0; j < 4; ++j) {
            short8 bw = *(const short8*)(w1t_e + (size_t)((w * 4 + j) * 16 + lr) * FIN + kk);
            acc[j] = __builtin_amdgcn_mfma_f32_16x16x32_bf16(a0, bw, acc[j], 0, 0, 0);
        }
    }
#pragma unroll
    for (int j = 0; j < 4; ++j)
#pragma unroll
        for (int r2 = 0; r2 < 4; ++r2) {
            int m = lg * 4 + r2;                      // pair row 0..15
            int n = (w * 4 + j) * 16 + lr;            // out col 0..127
            float h = acc[j][r2];
            h = h > 0.f ? h : (__expf(h) - 1.0f);
            int ng = (n >> 3) ^ (m & 7);
            H1s[m * HH1 + ng * 8 + (n & 7)] = f2bf(h);
        }
    __syncthreads();

    // -------- Layer 2 (swapped): H2T[96x16] = celu(W2T @ H1T + b2); wave w owns t6 in [3w, 3w+3)
    const short* w2t_e = w2tb + (size_t)e * HH2 * HH1;
    f32x4 acc2[3];
#pragma unroll
    for (int j = 0; j < 3; ++j)
#pragma unroll
        for (int r2 = 0; r2 < 4; ++r2)
            acc2[j][r2] = b2[e * HH2 + (w * 3 + j) * 16 + 4 * lg + r2];
#pragma unroll
    for (int ks = 0; ks < 4; ++ks) {
        int kk = ks * 32 + 8 * lg;
        int kg = kk >> 3;
        int m = lr;
        short8 bh = *(const short8*)&H1s[m * HH1 + ((kg ^ (m & 7)) << 3)];
#pragma unroll
        for (int j = 0; j < 3; ++j) {
            short8 aw = *(const short8*)(w2t_e + (size_t)((w * 3 + j) * 16 + lr) * HH1 + kk);
            acc2[j] = __builtin_amdgcn_mfma_f32_16x16x32_bf16(aw, bh, acc2[j], 0, 0, 0);
        }
    }
#pragma unroll
    for (int j = 0; j < 3; ++j)
#pragma unroll
        for (int r2 = 0; r2 < 4; ++r2) {
            int n2 = (w * 3 + j) * 16 + 4 * lg + r2;  // 0..95
            int m  = lr;                              // pair row
            float h = acc2[j][r2];
            h = h > 0.f ? h : (__expf(h) - 1.0f);
            H2s[m * 104 + n2] = f2bf(h);
        }
    __syncthreads();

    // -------- Layer 3: out[16x2] = H2 @ W3 + b3 (VALU, threads 0..31) ----
    if (t < TILE_P * 2) {
        int r = t >> 1, o = t & 1;
        if (r < cnt) {
            const float* w3e = W3 + (size_t)e * HH2 * 2;
            float s0 = b3[e * 2 + o], s1 = 0.f;
#pragma unroll
            for (int kb = 0; kb < 12; ++kb) {
                short8 h = *(const short8*)&H2s[r * 104 + kb * 8];
#pragma unroll
                for (int j = 0; j < 8; j += 2) {
                    s0 = fmaf(bf2f(h[j]),     w3e[(kb * 8 + j) * 2 + o],     s0);
                    s1 = fmaf(bf2f(h[j + 1]), w3e[(kb * 8 + j + 1) * 2 + o], s1);
                }
            }
            out[(size_t)rows_p[r] * 2 + o] = s0 + s1;
        }
    }
}

extern "C" void kernel_launch(void* const* d_in, const int* in_sizes, int n_in,
                              void* d_out, int out_size, void* d_ws, size_t ws_size,
                              hipStream_t stream)
{
    const int*   elements = (const int*)d_in[0];
    const int*   conn     = (const int*)d_in[1];
    const float* sym      = (const float*)d_in[2];
    const float* pairf    = (const float*)d_in[3];
    const float* W1       = (const float*)d_in[4];
    const float* b1       = (const float*)d_in[5];
    const float* W2       = (const float*)d_in[6];
    const float* b2       = (const float*)d_in[7];
    const float* W3       = (const float*)d_in[8];
    const float* b3       = (const float*)d_in[9];
    float* out = (float*)d_out;

    int* wsi    = (int*)d_ws;
    int* counts = wsi + WS_COUNTS;
    int* bucket = wsi + WS_BUCKET;

    short* bfb    = (short*)(wsi + WS_BF);
    short* symb   = bfb;
    short* pairfb = bfb + SYM_N;
    short* w1tb   = bfb + SYM_N + PAIR_N;
    short* w2tb   = bfb + SYM_N + PAIR_N + W1T_N;

    hipMemsetAsync((void*)counts, 0, NEXP * sizeof(int), stream);

    k_cvt_x<<<(SYM_N / 4 + PAIR_N / 4 + 255) / 256, 256, 0, stream>>>(sym, pairf, symb, pairfb);
    k_prep<<<1088, 256, 0, stream>>>(W1, W2, w1tb, w2tb, conn, elements, counts, bucket, out);
    k_moe<<<NEXP * TMAX, 128, 0, stream>>>(counts, bucket, conn, symb, pairfb,
                                           w1tb, w2tb, b1, b2, W3, b3, out);
}

// Round 4
// 68.713 us; speedup vs baseline: 2.3286x; 2.3286x over previous
//
#include <hip/hip_runtime.h>
#include <math.h>

typedef __attribute__((ext_vector_type(8))) short short8;
typedef __attribute__((ext_vector_type(4))) float f32x4;

namespace {
constexpr int NEL   = 4;
constexpr int NEXP  = 16;
constexpr int Bb    = 128;
constexpr int Aa    = 128;
constexpr int Cc    = 256;
constexpr int FATOM = 176;
constexpr int FPAIR = 32;
constexpr int FIN   = 384;
constexpr int HH1   = 128;
constexpr int HH2   = 96;
constexpr int NP    = Bb * Cc;               // 32768
constexpr int TILE_P = 16;                   // pairs per tile (1 block = 2 waves)
constexpr int BUCKET_CAP = 4096;             // pairs per expert cap (input ~2048 +- 44)
constexpr int TMAX = BUCKET_CAP / TILE_P;    // 256 tiles per expert

// ws int offsets
constexpr int WS_COUNTS = 0;                 // 16 ints
constexpr int WS_BUCKET = 64;                // 16 * 4096 ints
constexpr int WS_BF     = 65600;             // shorts from here (byte 262400, 16B aligned)
constexpr int SYM_N   = Bb * Aa * FATOM;     // 2,883,584
constexpr int PAIR_N  = Bb * Cc * FPAIR;     // 1,048,576
constexpr int W1T_N   = NEXP * HH1 * FIN;    // 786,432
constexpr int W2T_N   = NEXP * HH2 * HH1;    // 196,608

// fused prep grid layout
constexpr int CVT_BLOCKS = (SYM_N / 4 + PAIR_N / 4) / 256;  // 3840
constexpr int W1_BLOCKS  = 768;
constexpr int W2_BLOCKS  = 192;
constexpr int IDX_BLOCKS = NP / 256;                        // 128
constexpr int W1_BASE  = CVT_BLOCKS;
constexpr int W2_BASE  = W1_BASE + W1_BLOCKS;
constexpr int IDX_BASE = W2_BASE + W2_BLOCKS;
constexpr int PREP_GRID = IDX_BASE + IDX_BLOCKS;            // 4928
}

__device__ inline float bf2f(short s) {
    unsigned u = ((unsigned)(unsigned short)s) << 16;
    return __builtin_bit_cast(float, u);
}
__device__ inline short f2bf(float f) {
    unsigned u = __builtin_bit_cast(unsigned, f);
    unsigned r = (u + 0x7FFFu + ((u >> 16) & 1u)) >> 16;
    return (short)r;
}

// ---- fused prep: cvt_x | W1 transpose | W2 transpose | expert index ----
__global__ __launch_bounds__(256) void k_prep(
    const float* __restrict__ sym, const float* __restrict__ pairf,
    short* __restrict__ symb, short* __restrict__ pairfb,
    const float* __restrict__ W1, const float* __restrict__ W2,
    short* __restrict__ w1tb, short* __restrict__ w2tb,
    const int* __restrict__ conn, const int* __restrict__ elements,
    int* __restrict__ counts, int* __restrict__ bucket,
    float* __restrict__ out)
{
    __shared__ float T[32][33];          // transpose tile (also covers hist arrays)
    __shared__ int sh_cnt[NEXP], sh_base[NEXP];

    int bid = blockIdx.x;
    int t = threadIdx.x;

    if (bid < CVT_BLOCKS) {
        // ---- bf16 convert of sym/pair features, one float4 per thread ----
        int i = bid * 256 + t;
        constexpr int NS4 = SYM_N / 4;
        const float4* src; short* dst; int j;
        if (i < NS4) { src = (const float4*)sym;   dst = symb;   j = i; }
        else         { src = (const float4*)pairf; dst = pairfb; j = i - NS4; }
        float4 v = src[j];
        short4 o;
        o.x = f2bf(v.x); o.y = f2bf(v.y); o.z = f2bf(v.z); o.w = f2bf(v.w);
        *(short4*)(dst + 4 * (size_t)j) = o;
    } else if (bid < IDX_BASE) {
        // ---- LDS-tiled transpose+convert of W1 / W2 ----
        const float* src; short* dst; int K, N, k0, n0;
        if (bid < W2_BASE) {
            int b1i = bid - W1_BASE;
            int e = b1i / 48, tl = b1i % 48;
            K = FIN; N = HH1; k0 = (tl % 12) * 32; n0 = (tl / 12) * 32;
            src = W1 + (size_t)e * K * N;
            dst = w1tb + (size_t)e * N * K;
        } else {
            int b2i = bid - W2_BASE;
            int e = b2i / 12, tl = b2i % 12;
            K = HH1; N = HH2; k0 = (tl % 4) * 32; n0 = (tl / 4) * 32;
            src = W2 + (size_t)e * K * N;
            dst = w2tb + (size_t)e * N * K;
        }
        int tx = t & 31, ty = t >> 5;
#pragma unroll
        for (int j = 0; j < 4; ++j) {
            int r = ty + 8 * j;
            T[r][tx] = src[(size_t)(k0 + r) * N + n0 + tx];
        }
        __syncthreads();
#pragma unroll
        for (int j = 0; j < 4; ++j) {
            int r = ty + 8 * j;
            dst[(size_t)(n0 + r) * K + k0 + tx] = f2bf(T[tx][r]);
        }
    } else {
        // ---- expert index + aggregated bucket append ----
        int p = (bid - IDX_BASE) * 256 + t;
        if (t < NEXP) sh_cnt[t] = 0;
        __syncthreads();
        int e = -1, r = 0;
        {
            int c0 = conn[2 * p], c1 = conn[2 * p + 1];
            if (c0 != -1) {
                int b = p / Cc;
                int i0 = b * Aa + c0; if (i0 < 0) i0 += Bb * Aa;
                int i1 = b * Aa + c1; if (i1 < 0) i1 += Bb * Aa;
                e = elements[i0] * NEL + elements[i1];
            }
            if (e < 0 || e >= NEXP) {
                out[2 * p] = 0.f; out[2 * p + 1] = 0.f;
                e = -1;
            } else {
                r = atomicAdd(&sh_cnt[e], 1);
            }
        }
        __syncthreads();
        if (t < NEXP) sh_base[t] = (sh_cnt[t] > 0) ? atomicAdd(&counts[t], sh_cnt[t]) : 0;
        __syncthreads();
        if (e >= 0) {
            int pos = sh_base[e] + r;
            if (pos < BUCKET_CAP) bucket[e * BUCKET_CAP + pos] = p;
        }
    }
}

// ---- MFMA MoE: one 16-pair tile per block, split across 2 waves ----
__device__ inline const short* xptr(const short* symb, const short* pfb,
                                    int i0, int i1, int p, int kk)
{
    if (kk < FATOM)     return symb + (size_t)i0 * FATOM + kk;
    if (kk < 2 * FATOM) return symb + (size_t)i1 * FATOM + (kk - FATOM);
    return pfb + (size_t)p * FPAIR + (kk - 2 * FATOM);
}

__global__ __launch_bounds__(128, 4) void k_moe(
    const int* __restrict__ counts, const int* __restrict__ bucket,
    const int* __restrict__ conn,
    const short* __restrict__ symb, const short* __restrict__ pairfb,
    const short* __restrict__ w1tb, const short* __restrict__ w2tb,
    const float* __restrict__ b1, const float* __restrict__ b2,
    const float* __restrict__ W3, const float* __restrict__ b3,
    float* __restrict__ out)
{
    __shared__ short H1s[TILE_P * HH1];        // 4 KB, granule-XOR swizzled
    __shared__ short H2s[TILE_P * 104];        // 3.25 KB, stride 104
    __shared__ int rows_p[TILE_P], rows_i0[TILE_P], rows_i1[TILE_P];

    int e    = blockIdx.x >> 8;                // / TMAX
    int tile = blockIdx.x & (TMAX - 1);
    int cnt_e = counts[e];
    if (cnt_e > BUCKET_CAP) cnt_e = BUCKET_CAP;
    int base = tile * TILE_P;
    if (base >= cnt_e) return;
    int cnt = cnt_e - base; if (cnt > TILE_P) cnt = TILE_P;

    int t = threadIdx.x;
    if (t < TILE_P) {
        int idx = base + ((t < cnt) ? t : 0);
        int p = bucket[e * BUCKET_CAP + idx];
        int b = p / Cc;
        rows_p[t]  = p;
        rows_i0[t] = b * Aa + conn[2 * p];
        rows_i1[t] = b * Aa + conn[2 * p + 1];
    }
    __syncthreads();

    int w  = t >> 6;                            // wave 0/1
    int lr = t & 15, lg = (t >> 4) & 3;

    int i0a = rows_i0[lr], i1a = rows_i1[lr], pa = rows_p[lr];

    // -------- Layer 1: H1[16x128] = celu(X[16x384] @ W1 + b1); wave w owns n-cols [w*64, w*64+64)
    const short* w1t_e = w1tb + (size_t)e * HH1 * FIN;
    f32x4 acc[4];
#pragma unroll
    for (int j = 0; j < 4; ++j) {
        float bv = b1[e * HH1 + (w * 4 + j) * 16 + lr];
        acc[j] = (f32x4){bv, bv, bv, bv};
    }
    for (int ks = 0; ks < 12; ++ks) {
        int kk = ks * 32 + 8 * lg;
        short8 a0 = *(const short8*)xptr(symb, pairfb, i0a, i1a, pa, kk);
#pragma unroll
        for (int j = 0; j < 4; ++j) {
            short8 bw = *(const short8*)(w1t_e + (size_t)((w * 4 + j) * 16 + lr) * FIN + kk);
            acc[j] = __builtin_amdgcn_mfma_f32_16x16x32_bf16(a0, bw, acc[j], 0, 0, 0);
        }
    }
#pragma unroll
    for (int j = 0; j < 4; ++j)
#pragma unroll
        for (int r2 = 0; r2 < 4; ++r2) {
            int m = lg * 4 + r2;
            int n = (w * 4 + j) * 16 + lr;
            float h = acc[j][r2];
            h = h > 0.f ? h : (__expf(h) - 1.0f);
            int ng = (n >> 3) ^ (m & 7);
            H1s[m * HH1 + ng * 8 + (n & 7)] = f2bf(h);
        }
    __syncthreads();

    // -------- Layer 2 (swapped): H2T[96x16] = celu(W2T @ H1T + b2)
    const short* w2t_e = w2tb + (size_t)e * HH2 * HH1;
    f32x4 acc2[3];
#pragma unroll
    for (int j = 0; j < 3; ++j)
#pragma unroll
        for (int r2 = 0; r2 < 4; ++r2)
            acc2[j][r2] = b2[e * HH2 + (w * 3 + j) * 16 + 4 * lg + r2];
#pragma unroll
    for (int ks = 0; ks < 4; ++ks) {
        int kk = ks * 32 + 8 * lg;
        int kg = kk >> 3;
        int m = lr;
        short8 bh = *(const short8*)&H1s[m * HH1 + ((kg ^ (m & 7)) << 3)];
#pragma unroll
        for (int j = 0; j < 3; ++j) {
            short8 aw = *(const short8*)(w2t_e + (size_t)((w * 3 + j) * 16 + lr) * HH1 + kk);
            acc2[j] = __builtin_amdgcn_mfma_f32_16x16x32_bf16(aw, bh, acc2[j], 0, 0, 0);
        }
    }
#pragma unroll
    for (int j = 0; j < 3; ++j)
#pragma unroll
        for (int r2 = 0; r2 < 4; ++r2) {
            int n2 = (w * 3 + j) * 16 + 4 * lg + r2;
            int m  = lr;
            float h = acc2[j][r2];
            h = h > 0.f ? h : (__expf(h) - 1.0f);
            H2s[m * 104 + n2] = f2bf(h);
        }
    __syncthreads();

    // -------- Layer 3: out[16x2] = H2 @ W3 + b3 (VALU, threads 0..31) ----
    if (t < TILE_P * 2) {
        int r = t >> 1, o = t & 1;
        if (r < cnt) {
            const float* w3e = W3 + (size_t)e * HH2 * 2;
            float s0 = b3[e * 2 + o], s1 = 0.f;
#pragma unroll
            for (int kb = 0; kb < 12; ++kb) {
                short8 h = *(const short8*)&H2s[r * 104 + kb * 8];
#pragma unroll
                for (int j = 0; j < 8; j += 2) {
                    s0 = fmaf(bf2f(h[j]),     w3e[(kb * 8 + j) * 2 + o],     s0);
                    s1 = fmaf(bf2f(h[j + 1]), w3e[(kb * 8 + j + 1) * 2 + o], s1);
                }
            }
            out[(size_t)rows_p[r] * 2 + o] = s0 + s1;
        }
    }
}

extern "C" void kernel_launch(void* const* d_in, const int* in_sizes, int n_in,
                              void* d_out, int out_size, void* d_ws, size_t ws_size,
                              hipStream_t stream)
{
    const int*   elements = (const int*)d_in[0];
    const int*   conn     = (const int*)d_in[1];
    const float* sym      = (const float*)d_in[2];
    const float* pairf    = (const float*)d_in[3];
    const float* W1       = (const float*)d_in[4];
    const float* b1       = (const float*)d_in[5];
    const float* W2       = (const float*)d_in[6];
    const float* b2       = (const float*)d_in[7];
    const float* W3       = (const float*)d_in[8];
    const float* b3       = (const float*)d_in[9];
    float* out = (float*)d_out;

    int* wsi    = (int*)d_ws;
    int* counts = wsi + WS_COUNTS;
    int* bucket = wsi + WS_BUCKET;

    short* bfb    = (short*)(wsi + WS_BF);
    short* symb   = bfb;
    short* pairfb = bfb + SYM_N;
    short* w1tb   = bfb + SYM_N + PAIR_N;
    short* w2tb   = bfb + SYM_N + PAIR_N + W1T_N;

    hipMemsetAsync((void*)counts, 0, NEXP * sizeof(int), stream);

    k_prep<<<PREP_GRID, 256, 0, stream>>>(sym, pairf, symb, pairfb,
                                          W1, W2, w1tb, w2tb,
                                          conn, elements, counts, bucket, out);
    k_moe<<<NEXP * TMAX, 128, 0, stream>>>(counts, bucket, conn, symb, pairfb,
                                           w1tb, w2tb, b1, b2, W3, b3, out);
}

// Round 5
// 44.072 us; speedup vs baseline: 3.6305x; 1.5591x over previous
//
#include <hip/hip_runtime.h>
#include <math.h>

typedef __attribute__((ext_vector_type(8))) short short8;
typedef __attribute__((ext_vector_type(4))) float f32x4;

namespace {
constexpr int NEL   = 4;
constexpr int NEXP  = 16;
constexpr int Bb    = 128;
constexpr int Aa    = 128;
constexpr int Cc    = 256;
constexpr int FATOM = 176;
constexpr int FPAIR = 32;
constexpr int FIN   = 384;
constexpr int HH1   = 128;
constexpr int HH2   = 96;
constexpr int NP    = Bb * Cc;               // 32768
constexpr int TILE_P = 32;                   // pairs per tile (1 block = 2 waves)
constexpr int BUCKET_CAP = 4096;
constexpr int TMAX = BUCKET_CAP / TILE_P;    // 128 tiles per expert

// ws int offsets
constexpr int WS_COUNTS = 0;                 // 16 ints
constexpr int WS_BUCKET = 64;                // 16 * 4096 ints
constexpr int WS_BF     = 65600;             // shorts from here
constexpr int SYM_N   = Bb * Aa * FATOM;     // 2,883,584
constexpr int PAIR_N  = Bb * Cc * FPAIR;     // 1,048,576
constexpr int W1T_N   = NEXP * HH1 * FIN;    // 786,432  (packed [e][12][128][32])
constexpr int W2T_N   = NEXP * HH2 * HH1;    // 196,608  (packed [e][4][96][32])

// fused prep grid layout
constexpr int CVT_BLOCKS = (SYM_N / 4 + PAIR_N / 4) / 256;  // 3840
constexpr int W1_BLOCKS  = 768;
constexpr int W2_BLOCKS  = 192;
constexpr int IDX_BLOCKS = NP / 256;                        // 128
constexpr int W1_BASE  = CVT_BLOCKS;
constexpr int W2_BASE  = W1_BASE + W1_BLOCKS;
constexpr int IDX_BASE = W2_BASE + W2_BLOCKS;
constexpr int PREP_GRID = IDX_BASE + IDX_BLOCKS;            // 4928
}

__device__ inline float bf2f(short s) {
    unsigned u = ((unsigned)(unsigned short)s) << 16;
    return __builtin_bit_cast(float, u);
}
__device__ inline short f2bf(float f) {
    unsigned u = __builtin_bit_cast(unsigned, f);
    unsigned r = (u + 0x7FFFu + ((u >> 16) & 1u)) >> 16;
    return (short)r;
}

// ---- fused prep: cvt_x | W1 pack | W2 pack | expert index ----
__global__ __launch_bounds__(256) void k_prep(
    const float* __restrict__ sym, const float* __restrict__ pairf,
    short* __restrict__ symb, short* __restrict__ pairfb,
    const float* __restrict__ W1, const float* __restrict__ W2,
    short* __restrict__ w1tb, short* __restrict__ w2tb,
    const int* __restrict__ conn, const int* __restrict__ elements,
    int* __restrict__ counts, int* __restrict__ bucket,
    float* __restrict__ out)
{
    __shared__ float T[32][33];
    __shared__ int sh_cnt[NEXP], sh_base[NEXP];

    int bid = blockIdx.x;
    int t = threadIdx.x;

    if (bid < CVT_BLOCKS) {
        int i = bid * 256 + t;
        constexpr int NS4 = SYM_N / 4;
        const float4* src; short* dst; int j;
        if (i < NS4) { src = (const float4*)sym;   dst = symb;   j = i; }
        else         { src = (const float4*)pairf; dst = pairfb; j = i - NS4; }
        float4 v = src[j];
        short4 o;
        o.x = f2bf(v.x); o.y = f2bf(v.y); o.z = f2bf(v.z); o.w = f2bf(v.w);
        *(short4*)(dst + 4 * (size_t)j) = o;
    } else if (bid < IDX_BASE) {
        // LDS-tiled transpose; write K-step-packed layout [e][ks][n][32]
        const float* src; short* dst; int K, N, k0, n0;
        if (bid < W2_BASE) {
            int b1i = bid - W1_BASE;
            int e = b1i / 48, tl = b1i % 48;
            K = FIN; N = HH1; k0 = (tl % 12) * 32; n0 = (tl / 12) * 32;
            src = W1 + (size_t)e * K * N;
            dst = w1tb + (size_t)e * 12 * HH1 * 32;
        } else {
            int b2i = bid - W2_BASE;
            int e = b2i / 12, tl = b2i % 12;
            K = HH1; N = HH2; k0 = (tl % 4) * 32; n0 = (tl / 4) * 32;
            src = W2 + (size_t)e * K * N;
            dst = w2tb + (size_t)e * 4 * HH2 * 32;
        }
        int tx = t & 31, ty = t >> 5;
        int ks = k0 >> 5;
#pragma unroll
        for (int j = 0; j < 4; ++j) {
            int r = ty + 8 * j;
            T[r][tx] = src[(size_t)(k0 + r) * N + n0 + tx];
        }
        __syncthreads();
#pragma unroll
        for (int j = 0; j < 4; ++j) {
            int n = n0 + ty + 8 * j;                   // dst row (col of W)
            dst[(size_t)(ks * N + n) * 32 + tx] = f2bf(T[tx][ty + 8 * j]);
        }
    } else {
        int p = (bid - IDX_BASE) * 256 + t;
        if (t < NEXP) sh_cnt[t] = 0;
        __syncthreads();
        int e = -1, r = 0;
        {
            int c0 = conn[2 * p], c1 = conn[2 * p + 1];
            if (c0 != -1) {
                int b = p / Cc;
                int i0 = b * Aa + c0; if (i0 < 0) i0 += Bb * Aa;
                int i1 = b * Aa + c1; if (i1 < 0) i1 += Bb * Aa;
                e = elements[i0] * NEL + elements[i1];
            }
            if (e < 0 || e >= NEXP) {
                out[2 * p] = 0.f; out[2 * p + 1] = 0.f;
                e = -1;
            } else {
                r = atomicAdd(&sh_cnt[e], 1);
            }
        }
        __syncthreads();
        if (t < NEXP) sh_base[t] = (sh_cnt[t] > 0) ? atomicAdd(&counts[t], sh_cnt[t]) : 0;
        __syncthreads();
        if (e >= 0) {
            int pos = sh_base[e] + r;
            if (pos < BUCKET_CAP) bucket[e * BUCKET_CAP + pos] = p;
        }
    }
}

// ---- MFMA MoE: 32-pair tile per block, 2 waves, wave w owns cols [64w,64w+64) ----
__global__ __launch_bounds__(128, 2) void k_moe(
    const int* __restrict__ counts, const int* __restrict__ bucket,
    const int* __restrict__ conn,
    const short* __restrict__ symb, const short* __restrict__ pairfb,
    const short* __restrict__ w1tb, const short* __restrict__ w2tb,
    const float* __restrict__ b1, const float* __restrict__ b2,
    const float* __restrict__ W3, const float* __restrict__ b3,
    float* __restrict__ out)
{
    __shared__ short H1s[TILE_P * HH1];        // 8 KB, granule-XOR swizzled
    __shared__ short H2s[TILE_P * 104];        // 6.5 KB
    __shared__ int rows_p[TILE_P], rows_i0[TILE_P], rows_i1[TILE_P];

    int e    = blockIdx.x >> 7;                // / TMAX
    int tile = blockIdx.x & (TMAX - 1);
    int cnt_e = counts[e];
    if (cnt_e > BUCKET_CAP) cnt_e = BUCKET_CAP;
    int base = tile * TILE_P;
    if (base >= cnt_e) return;
    int cnt = cnt_e - base; if (cnt > TILE_P) cnt = TILE_P;

    int t = threadIdx.x;
    if (t < TILE_P) {
        int idx = base + ((t < cnt) ? t : 0);
        int p = bucket[e * BUCKET_CAP + idx];
        int b = p / Cc;
        rows_p[t]  = p;
        rows_i0[t] = b * Aa + conn[2 * p];
        rows_i1[t] = b * Aa + conn[2 * p + 1];
    }
    __syncthreads();

    int w  = t >> 6;                            // wave 0/1
    int lr = t & 15, lg = (t >> 4) & 3;

    // branch-free A-region bases per m-frag
    const short* baseFA[2];
    const short* baseFB[2];
    const short* basePF[2];
#pragma unroll
    for (int mi = 0; mi < 2; ++mi) {
        int i0 = rows_i0[lr + 16 * mi];
        int i1 = rows_i1[lr + 16 * mi];
        int p  = rows_p[lr + 16 * mi];
        baseFA[mi] = symb + (size_t)i0 * FATOM;
        baseFB[mi] = symb + (size_t)i1 * FATOM - FATOM;
        basePF[mi] = pairfb + (size_t)p * FPAIR - 2 * FATOM;
    }

    // -------- Layer 1: H1[32x128] = celu(X[32x384] @ W1 + b1) --------
    const short* w1p_e = w1tb + (size_t)e * 12 * HH1 * 32;
    f32x4 acc[2][4];
#pragma unroll
    for (int j = 0; j < 4; ++j) {
        float bv = b1[e * HH1 + w * 64 + j * 16 + lr];
        acc[0][j] = (f32x4){bv, bv, bv, bv};
        acc[1][j] = acc[0][j];
    }
#pragma unroll
    for (int ks = 0; ks < 12; ++ks) {
        int kk = ks * 32 + 8 * lg;
        short8 a[2];
#pragma unroll
        for (int mi = 0; mi < 2; ++mi) {
            const short* bp;
            if (ks < 5)       bp = baseFA[mi];
            else if (ks == 5) bp = (kk < FATOM) ? baseFA[mi] : baseFB[mi];
            else if (ks < 11) bp = baseFB[mi];
            else              bp = basePF[mi];
            a[mi] = *(const short8*)(bp + kk);
        }
        const short* wchunk = w1p_e + ks * (HH1 * 32);
#pragma unroll
        for (int j = 0; j < 4; ++j) {
            int n = w * 64 + j * 16 + lr;
            short8 bw = *(const short8*)(wchunk + n * 32 + 8 * lg);
            acc[0][j] = __builtin_amdgcn_mfma_f32_16x16x32_bf16(a[0], bw, acc[0][j], 0, 0, 0);
            acc[1][j] = __builtin_amdgcn_mfma_f32_16x16x32_bf16(a[1], bw, acc[1][j], 0, 0, 0);
        }
    }
#pragma unroll
    for (int mi = 0; mi < 2; ++mi)
#pragma unroll
        for (int j = 0; j < 4; ++j)
#pragma unroll
            for (int r2 = 0; r2 < 4; ++r2) {
                int m = mi * 16 + lg * 4 + r2;
                int n = w * 64 + j * 16 + lr;
                float h = acc[mi][j][r2];
                h = h > 0.f ? h : (__expf(h) - 1.0f);
                int ng = (n >> 3) ^ (m & 7);
                H1s[m * HH1 + ng * 8 + (n & 7)] = f2bf(h);
            }
    __syncthreads();

    // -------- Layer 2 (swapped): wave w owns n2 in [48w, 48w+48) --------
    const short* w2p_e = w2tb + (size_t)e * 4 * HH2 * 32;
    f32x4 acc2[3][2];
#pragma unroll
    for (int j = 0; j < 3; ++j) {
#pragma unroll
        for (int r2 = 0; r2 < 4; ++r2) {
            float bv = b2[e * HH2 + (w * 3 + j) * 16 + 4 * lg + r2];
            acc2[j][0][r2] = bv; acc2[j][1][r2] = bv;
        }
    }
#pragma unroll
    for (int ks = 0; ks < 4; ++ks) {
        int kk = ks * 32 + 8 * lg;
        int kg = kk >> 3;
        short8 bh[2];
#pragma unroll
        for (int mi = 0; mi < 2; ++mi) {
            int m = mi * 16 + lr;
            bh[mi] = *(const short8*)&H1s[m * HH1 + ((kg ^ (m & 7)) << 3)];
        }
        const short* wchunk = w2p_e + ks * (HH2 * 32);
#pragma unroll
        for (int j = 0; j < 3; ++j) {
            int n2r = (w * 3 + j) * 16 + lr;
            short8 aw = *(const short8*)(wchunk + n2r * 32 + 8 * lg);
            acc2[j][0] = __builtin_amdgcn_mfma_f32_16x16x32_bf16(aw, bh[0], acc2[j][0], 0, 0, 0);
            acc2[j][1] = __builtin_amdgcn_mfma_f32_16x16x32_bf16(aw, bh[1], acc2[j][1], 0, 0, 0);
        }
    }
#pragma unroll
    for (int j = 0; j < 3; ++j)
#pragma unroll
        for (int mi = 0; mi < 2; ++mi)
#pragma unroll
            for (int r2 = 0; r2 < 4; ++r2) {
                int n2 = (w * 3 + j) * 16 + 4 * lg + r2;
                int m  = mi * 16 + lr;
                float h = acc2[j][mi][r2];
                h = h > 0.f ? h : (__expf(h) - 1.0f);
                H2s[m * 104 + n2] = f2bf(h);
            }
    __syncthreads();

    // -------- Layer 3: out[32x2] = H2 @ W3 + b3 (VALU, threads 0..63) ----
    if (t < TILE_P * 2) {
        int r = t >> 1, o = t & 1;
        if (r < cnt) {
            const float* w3e = W3 + (size_t)e * HH2 * 2;
            float s0 = b3[e * 2 + o], s1 = 0.f;
#pragma unroll
            for (int kb = 0; kb < 12; ++kb) {
                short8 h = *(const short8*)&H2s[r * 104 + kb * 8];
#pragma unroll
                for (int j = 0; j < 8; j += 2) {
                    s0 = fmaf(bf2f(h[j]),     w3e[(kb * 8 + j) * 2 + o],     s0);
                    s1 = fmaf(bf2f(h[j + 1]), w3e[(kb * 8 + j + 1) * 2 + o], s1);
                }
            }
            out[(size_t)rows_p[r] * 2 + o] = s0 + s1;
        }
    }
}

extern "C" void kernel_launch(void* const* d_in, const int* in_sizes, int n_in,
                              void* d_out, int out_size, void* d_ws, size_t ws_size,
                              hipStream_t stream)
{
    const int*   elements = (const int*)d_in[0];
    const int*   conn     = (const int*)d_in[1];
    const float* sym      = (const float*)d_in[2];
    const float* pairf    = (const float*)d_in[3];
    const float* W1       = (const float*)d_in[4];
    const float* b1       = (const float*)d_in[5];
    const float* W2       = (const float*)d_in[6];
    const float* b2       = (const float*)d_in[7];
    const float* W3       = (const float*)d_in[8];
    const float* b3       = (const float*)d_in[9];
    float* out = (float*)d_out;

    int* wsi    = (int*)d_ws;
    int* counts = wsi + WS_COUNTS;
    int* bucket = wsi + WS_BUCKET;

    short* bfb    = (short*)(wsi + WS_BF);
    short* symb   = bfb;
    short* pairfb = bfb + SYM_N;
    short* w1tb   = bfb + SYM_N + PAIR_N;
    short* w2tb   = bfb + SYM_N + PAIR_N + W1T_N;

    hipMemsetAsync((void*)counts, 0, NEXP * sizeof(int), stream);

    k_prep<<<PREP_GRID, 256, 0, stream>>>(sym, pairf, symb, pairfb,
                                          W1, W2, w1tb, w2tb,
                                          conn, elements, counts, bucket, out);
    k_moe<<<NEXP * TMAX, 128, 0, stream>>>(counts, bucket, conn, symb, pairfb,
                                           w1tb, w2tb, b1, b2, W3, b3, out);
}